// Round 3
// baseline (1734.851 us; speedup 1.0000x reference)
//
#include <hip/hip_runtime.h>

#define BATCH 4096

typedef __attribute__((ext_vector_type(8))) short bf16x8;
typedef __attribute__((ext_vector_type(4))) float f32x4;

// Manual RNE float->bf16 (round half to even), matches HW/NumPy for normal finite values.
__device__ __forceinline__ unsigned short f2bf(float f) {
    union { float f; unsigned u; } v; v.f = f;
    unsigned r = v.u + 0x7fffu + ((v.u >> 16) & 1u);
    return (unsigned short)(r >> 16);
}
__device__ __forceinline__ unsigned packbf(float a, float b) {
    return (unsigned)f2bf(a) | ((unsigned)f2bf(b) << 16);
}

// 16 features for one x: o[0..3] = cos(1x..8x) pairs, o[4..7] = sin(1x..8x) pairs (bf16x2).
__device__ __forceinline__ void feats16(float x, unsigned o[8]) {
    float c1 = __cosf(x), s1 = __sinf(x);
    float cs[8], sn[8];
    cs[0] = c1; sn[0] = s1;
    #pragma unroll
    for (int k = 1; k < 8; ++k) {
        cs[k] = c1 * cs[k-1] - s1 * sn[k-1];
        sn[k] = s1 * cs[k-1] + c1 * sn[k-1];
    }
    #pragma unroll
    for (int k = 0; k < 4; ++k) {
        o[k]     = packbf(cs[2*k], cs[2*k+1]);
        o[4 + k] = packbf(sn[2*k], sn[2*k+1]);
    }
}

// Async global->LDS, 16 B per lane. LDS dest is wave-uniform base; HW adds lane*16.
__device__ __forceinline__ void gload_lds16(const void* g, void* l) {
    __builtin_amdgcn_global_load_lds(
        (__attribute__((address_space(1))) void*)(g),
        (__attribute__((address_space(3))) void*)(l), 16, 0, 0);
}

// ---------------- one-shot precompute kernels ----------------

// C [2][OUT][IN][8] f32  ->  B [OUT][IN*16] bf16, k = i*16 + d*8 + g
// (matches feats16 output order: t=0..7 cos, 8..15 sin)
template <int IN, int OUT>
__global__ void conv_C(const float* __restrict__ C, unsigned short* __restrict__ B) {
    const int i = blockIdx.x * 256 + threadIdx.x;
    const int j = blockIdx.y;
    const float* c0 = C + ((size_t)j * IN + i) * 8;            // d=0 (cos) plane
    const float* c1 = c0 + (size_t)OUT * IN * 8;               // d=1 (sin) plane
    const float4 a0 = *(const float4*)c0;
    const float4 a1 = *(const float4*)(c0 + 4);
    const float4 s0 = *(const float4*)c1;
    const float4 s1 = *(const float4*)(c1 + 4);
    unsigned short* dst = B + ((size_t)j * IN + i) * 16;
    *(uint4*)dst       = make_uint4(packbf(a0.x, a0.y), packbf(a0.z, a0.w),
                                    packbf(a1.x, a1.y), packbf(a1.z, a1.w));
    *(uint4*)(dst + 8) = make_uint4(packbf(s0.x, s0.y), packbf(s0.z, s0.w),
                                    packbf(s1.x, s1.y), packbf(s1.z, s1.w));
}

// x [4096][768] f32 -> A1 [4096][768*16] bf16 (features of the input layer)
__global__ void feats_x_kernel(const float* __restrict__ x, unsigned short* __restrict__ A) {
    const size_t idx = (size_t)blockIdx.x * 256 + threadIdx.x;   // (b,i) linear
    unsigned o[8];
    feats16(x[idx], o);
    unsigned short* dst = A + idx * 16;
    *(uint4*)dst       = make_uint4(o[0], o[1], o[2], o[3]);
    *(uint4*)(dst + 8) = make_uint4(o[4], o[5], o[6], o[7]);
}

// Deterministic split-K reduce + feature epilogue:
// y = sum_z P[z][b][j] + bias[j]; A[(b*N+j)*16..] = feats16(y) (bf16).
// Fixed summation order -> bitwise-identical output every call.
template <int N, int KSPLIT>
__global__ void reduce_feats(const float* __restrict__ P, const float* __restrict__ bias,
                             unsigned short* __restrict__ A) {
    const size_t idx = (size_t)blockIdx.x * 256 + threadIdx.x;   // (b,j) linear
    float s = P[idx];
    #pragma unroll
    for (int z = 1; z < KSPLIT; ++z) s += P[(size_t)z * BATCH * N + idx];
    s += bias[idx % N];
    unsigned o[8];
    feats16(s, o);
    unsigned short* dst = A + idx * 16;
    *(uint4*)dst       = make_uint4(o[0], o[1], o[2], o[3]);
    *(uint4*)(dst + 8) = make_uint4(o[4], o[5], o[6], o[7]);
}

// Deterministic split-K reduction: out[b][j] = sum_z P[z][b][j] + bias[j].
template <int N, int KSPLIT>
__global__ void reduce_out(const float* __restrict__ P, const float* __restrict__ bias,
                           float* __restrict__ out) {
    const size_t idx = ((size_t)blockIdx.x * 256 + threadIdx.x) * 4;   // float4 granule
    const int j = (int)(idx % N);                                       // N % 4 == 0
    float4 s = *(const float4*)(P + idx);
    #pragma unroll
    for (int z = 1; z < KSPLIT; ++z) {
        const float4 v = *(const float4*)(P + (size_t)z * BATCH * N + idx);
        s.x += v.x; s.y += v.y; s.z += v.z; s.w += v.w;
    }
    const float4 bv = *(const float4*)(bias + j);
    s.x += bv.x; s.y += bv.y; s.z += bv.z; s.w += bv.w;
    *(float4*)(out + idx) = s;
}

// ---------------- main bf16 GEMM (m97 structure, split-K) ----------------
// A [4096][K] bf16 row-major, B [N][K] bf16 row-major (B^T GEMM).
// Tile 128x128, BK=64, 4 waves (2x2), global_load_lds width-16 staging, 2 barriers/k-step.
// All layers use split-K (KSPLIT z-planes) so grid >= 1024 blocks = 4 blocks/CU
// (round-2 profile: 512 blocks -> 2 blocks/CU -> OccupancyPercent 23.5, MfmaUtil 23).
// Epilogue writes deterministic f32 partials; reduce_feats / reduce_out finish.
template <int K, int N, int KSPLIT>
__global__ __launch_bounds__(256, 2)
void kan_gemm(const unsigned short* __restrict__ A,
              const unsigned short* __restrict__ B,
              float* __restrict__ P)
{
    __shared__ unsigned short As[128 * 64];   // 16 KB, linear (required by global_load_lds)
    __shared__ unsigned short Bs[128 * 64];   // 16 KB

    const int tid  = threadIdx.x;
    const int lane = tid & 63;
    const int wave = tid >> 6;          // 0..3
    const int wm   = wave >> 1;         // wave row -> 64 batch rows
    const int wn   = wave & 1;          // wave col -> 64 out cols
    const int fr   = lane & 15;
    const int fq   = lane >> 4;

    // XCD-chunked bijective swizzle over the (bx,by) tile plane (NWG % 8 == 0 for all shapes)
    constexpr int NBX = BATCH / 128;
    constexpr int NBY = N / 128;
    constexpr int NWG = NBX * NBY;
    const int wg  = blockIdx.y * NBX + blockIdx.x;
    const int swz = (wg & 7) * (NWG >> 3) + (wg >> 3);
    const int row0 = (swz % NBX) * 128;   // batch
    const int col0 = (swz / NBX) * 128;   // out features

    constexpr int KCH = K / KSPLIT;
    const int k0 = (int)blockIdx.z * KCH;

    const int srow = lane >> 3;           // 0..7: row within the wave's 8-row staging stripe
    const int scol = (lane & 7) * 16;     // byte col within the 128 B row

    f32x4 acc[4][4] = {};

    for (int kt = k0 >> 6; kt < (k0 + KCH) >> 6; ++kt) {
        __syncthreads();   // previous tile's ds_reads done before overwrite
        #pragma unroll
        for (int r = 0; r < 4; ++r) {
            const int rr = r * 32 + wave * 8;          // wave-uniform stripe base
            gload_lds16((const char*)A + ((size_t)(row0 + rr + srow) * K + (size_t)kt * 64) * 2 + scol,
                        (char*)&As[rr * 64]);
            gload_lds16((const char*)B + ((size_t)(col0 + rr + srow) * K + (size_t)kt * 64) * 2 + scol,
                        (char*)&Bs[rr * 64]);
        }
        __syncthreads();   // compiler emits vmcnt(0) drain here

        #pragma unroll
        for (int ks = 0; ks < 2; ++ks) {
            bf16x8 af[4], bfm[4];
            #pragma unroll
            for (int m = 0; m < 4; ++m)
                af[m] = *(const bf16x8*)&As[(wm * 64 + m * 16 + fr) * 64 + ks * 32 + fq * 8];
            #pragma unroll
            for (int n = 0; n < 4; ++n)
                bfm[n] = *(const bf16x8*)&Bs[(wn * 64 + n * 16 + fr) * 64 + ks * 32 + fq * 8];
            #pragma unroll
            for (int m = 0; m < 4; ++m)
                #pragma unroll
                for (int n = 0; n < 4; ++n)
                    acc[m][n] = __builtin_amdgcn_mfma_f32_16x16x32_bf16(
                        af[m], bfm[n], acc[m][n], 0, 0, 0);
        }
    }

    // Epilogue: write split-K partial plane. C/D layout: col = lane&15, row = (lane>>4)*4+reg.
    float* Pz = P + (size_t)blockIdx.z * BATCH * N;
    #pragma unroll
    for (int n = 0; n < 4; ++n) {
        const int gc = col0 + wn * 64 + n * 16 + fr;
        #pragma unroll
        for (int m = 0; m < 4; ++m) {
            const int gr0 = row0 + wm * 64 + m * 16 + fq * 4;
            #pragma unroll
            for (int q = 0; q < 4; ++q)
                Pz[(size_t)(gr0 + q) * N + gc] = acc[m][n][q];
        }
    }
}

extern "C" void kernel_launch(void* const* d_in, const int* in_sizes, int n_in,
                              void* d_out, int out_size, void* d_ws, size_t ws_size,
                              hipStream_t stream) {
    (void)in_sizes; (void)n_in; (void)ws_size; (void)out_size;
    const float* x  = (const float*)d_in[0];   // [4096][768]
    const float* C1 = (const float*)d_in[1];   // [2][2048][768][8]
    const float* b1 = (const float*)d_in[2];   // [2048]
    const float* C2 = (const float*)d_in[3];   // [2][2048][2048][8]
    const float* b2 = (const float*)d_in[4];   // [2048]
    const float* C3 = (const float*)d_in[5];   // [2][512][2048][8]
    const float* b3 = (const float*)d_in[6];   // [512]
    float* out = (float*)d_out;                // [4096][512]

    // Workspace layout, lifetime-aliased. Peak use = 554 MB (round-2 proved >= 688 OK).
    //   timeline:  A1,B1 -> gemm1 -> P1 -> reduce1 -> A2
    //              B2 (aliases dead A1+B1) -> gemm2 -> P2 -> reduce2 -> A3 (aliases dead B2/P1/A2-head)
    //              B3, P3 (alias dead A2 tail) -> gemm3 -> reduce_out
    char* ws = (char*)d_ws;
    const size_t SZ_A1  = (size_t)4096 * 12288 * 2;      // 100,663,296
    const size_t SZ_B1  = (size_t)2048 * 12288 * 2;      //  50,331,648
    const size_t SZ_P12 = (size_t)2 * 4096 * 2048 * 4;   //  67,108,864
    const size_t SZ_A2  = (size_t)4096 * 32768 * 2;      // 268,435,456
    unsigned short* A1 = (unsigned short*)(ws);
    unsigned short* B1 = (unsigned short*)(ws + SZ_A1);
    float*          P1 = (float*)(ws + SZ_A1 + SZ_B1);                    // [151.0, 218.1) MB
    unsigned short* A2 = (unsigned short*)(ws + SZ_A1 + SZ_B1 + SZ_P12);  // [218.1, 486.5) MB
    unsigned short* B2 = (unsigned short*)(ws);                           // [0, 134.2) MB
    float*          P2 = (float*)(ws + SZ_A1 + SZ_B1 + SZ_P12 + SZ_A2);   // [486.5, 553.6) MB
    unsigned short* A3 = (unsigned short*)(ws);                           // [0, 268.4) MB
    unsigned short* B3 = (unsigned short*)(ws + SZ_A2);                   // [268.4, 302.0) MB
    float*          P3 = (float*)(ws + SZ_A2 + (size_t)512 * 32768 * 2);  // [302.0, 369.1) MB

    // ---- layer 1: (4096 x 12288) x (2048 x 12288)^T, split-K x2 -> feats -> A2
    conv_C<768, 2048><<<dim3(768 / 256, 2048), 256, 0, stream>>>(C1, B1);
    feats_x_kernel<<<dim3((4096 * 768) / 256), 256, 0, stream>>>(x, A1);
    kan_gemm<12288, 2048, 2><<<dim3(32, 16, 2), 256, 0, stream>>>(A1, B1, P1);
    reduce_feats<2048, 2><<<dim3((BATCH * 2048) / 256), 256, 0, stream>>>(P1, b1, A2);

    // ---- layer 2: (4096 x 32768) x (2048 x 32768)^T, split-K x2 -> feats -> A3
    conv_C<2048, 2048><<<dim3(2048 / 256, 2048), 256, 0, stream>>>(C2, B2);   // after gemm1 (alias)
    kan_gemm<32768, 2048, 2><<<dim3(32, 16, 2), 256, 0, stream>>>(A2, B2, P2);
    reduce_feats<2048, 2><<<dim3((BATCH * 2048) / 256), 256, 0, stream>>>(P2, b2, A3);

    // ---- layer 3: (4096 x 32768) x (512 x 32768)^T, split-K x8, deterministic reduce
    conv_C<2048, 512><<<dim3(2048 / 256, 512), 256, 0, stream>>>(C3, B3);     // after reduce2 (alias)
    kan_gemm<32768, 512, 8><<<dim3(32, 4, 8), 256, 0, stream>>>(A3, B3, P3);
    reduce_out<512, 8><<<dim3((BATCH * 512 / 4) / 256), 256, 0, stream>>>(P3, b3, out);
}

// Round 4
// 1722.979 us; speedup vs baseline: 1.0069x; 1.0069x over previous
//
#include <hip/hip_runtime.h>

#define BATCH 4096

typedef __attribute__((ext_vector_type(8))) short bf16x8;
typedef __attribute__((ext_vector_type(4))) float f32x4;

// Manual RNE float->bf16 (round half to even), matches HW/NumPy for normal finite values.
__device__ __forceinline__ unsigned short f2bf(float f) {
    union { float f; unsigned u; } v; v.f = f;
    unsigned r = v.u + 0x7fffu + ((v.u >> 16) & 1u);
    return (unsigned short)(r >> 16);
}
__device__ __forceinline__ unsigned packbf(float a, float b) {
    return (unsigned)f2bf(a) | ((unsigned)f2bf(b) << 16);
}

// 16 features for one x: o[0..3] = cos(1x..8x) pairs, o[4..7] = sin(1x..8x) pairs (bf16x2).
__device__ __forceinline__ void feats16(float x, unsigned o[8]) {
    float c1 = __cosf(x), s1 = __sinf(x);
    float cs[8], sn[8];
    cs[0] = c1; sn[0] = s1;
    #pragma unroll
    for (int k = 1; k < 8; ++k) {
        cs[k] = c1 * cs[k-1] - s1 * sn[k-1];
        sn[k] = s1 * cs[k-1] + c1 * sn[k-1];
    }
    #pragma unroll
    for (int k = 0; k < 4; ++k) {
        o[k]     = packbf(cs[2*k], cs[2*k+1]);
        o[4 + k] = packbf(sn[2*k], sn[2*k+1]);
    }
}

// Async global->LDS, 16 B per lane. LDS dest is wave-uniform base; HW adds lane*16.
__device__ __forceinline__ void gload_lds16(const void* g, void* l) {
    __builtin_amdgcn_global_load_lds(
        (__attribute__((address_space(1))) void*)(g),
        (__attribute__((address_space(3))) void*)(l), 16, 0, 0);
}

// ---------------- one-shot precompute kernels ----------------

// C [2][OUT][IN][8] f32  ->  B [OUT][IN*16] bf16, k = i*16 + d*8 + g
template <int IN, int OUT>
__global__ void conv_C(const float* __restrict__ C, unsigned short* __restrict__ B) {
    const int i = blockIdx.x * 256 + threadIdx.x;
    const int j = blockIdx.y;
    const float* c0 = C + ((size_t)j * IN + i) * 8;            // d=0 (cos) plane
    const float* c1 = c0 + (size_t)OUT * IN * 8;               // d=1 (sin) plane
    const float4 a0 = *(const float4*)c0;
    const float4 a1 = *(const float4*)(c0 + 4);
    const float4 s0 = *(const float4*)c1;
    const float4 s1 = *(const float4*)(c1 + 4);
    unsigned short* dst = B + ((size_t)j * IN + i) * 16;
    *(uint4*)dst       = make_uint4(packbf(a0.x, a0.y), packbf(a0.z, a0.w),
                                    packbf(a1.x, a1.y), packbf(a1.z, a1.w));
    *(uint4*)(dst + 8) = make_uint4(packbf(s0.x, s0.y), packbf(s0.z, s0.w),
                                    packbf(s1.x, s1.y), packbf(s1.z, s1.w));
}

// x [4096][768] f32 -> A1 [4096][768*16] bf16 (features of the input layer)
__global__ void feats_x_kernel(const float* __restrict__ x, unsigned short* __restrict__ A) {
    const size_t idx = (size_t)blockIdx.x * 256 + threadIdx.x;   // (b,i) linear
    unsigned o[8];
    feats16(x[idx], o);
    unsigned short* dst = A + idx * 16;
    *(uint4*)dst       = make_uint4(o[0], o[1], o[2], o[3]);
    *(uint4*)(dst + 8) = make_uint4(o[4], o[5], o[6], o[7]);
}

// Deterministic split-K reduce + feature epilogue (fixed order -> bitwise-stable).
template <int N, int KSPLIT>
__global__ void reduce_feats(const float* __restrict__ P, const float* __restrict__ bias,
                             unsigned short* __restrict__ A) {
    const size_t idx = (size_t)blockIdx.x * 256 + threadIdx.x;   // (b,j) linear
    float s = P[idx];
    #pragma unroll
    for (int z = 1; z < KSPLIT; ++z) s += P[(size_t)z * BATCH * N + idx];
    s += bias[idx % N];
    unsigned o[8];
    feats16(s, o);
    unsigned short* dst = A + idx * 16;
    *(uint4*)dst       = make_uint4(o[0], o[1], o[2], o[3]);
    *(uint4*)(dst + 8) = make_uint4(o[4], o[5], o[6], o[7]);
}

// Deterministic split-K reduction: out[b][j] = sum_z P[z][b][j] + bias[j].
template <int N, int KSPLIT>
__global__ void reduce_out(const float* __restrict__ P, const float* __restrict__ bias,
                           float* __restrict__ out) {
    const size_t idx = ((size_t)blockIdx.x * 256 + threadIdx.x) * 4;   // float4 granule
    const int j = (int)(idx % N);                                       // N % 4 == 0
    float4 s = *(const float4*)(P + idx);
    #pragma unroll
    for (int z = 1; z < KSPLIT; ++z) {
        const float4 v = *(const float4*)(P + (size_t)z * BATCH * N + idx);
        s.x += v.x; s.y += v.y; s.z += v.z; s.w += v.w;
    }
    const float4 bv = *(const float4*)(bias + j);
    s.x += bv.x; s.y += bv.y; s.z += bv.z; s.w += bv.w;
    *(float4*)(out + idx) = s;
}

// ---------------- main bf16 GEMM: 128x128 tile + dbuf LDS + counted vmcnt ----------------
// A [4096][K] bf16 row-major, B [N][K] bf16 row-major (B^T GEMM).
// BK=64, 4 waves (2x2). Occupancy is reg-capped at 2 blocks/CU (76 arch + 64 acc = 140 regs,
// past the 128 cliff), so latency hiding must come from within-wave prefetch:
// double-buffered LDS, next tile's 8 global_load_lds issued BEFORE current tile's MFMA,
// s_waitcnt vmcnt(8) (never 0 mid-loop) + raw s_barrier (no __syncthreads drain).
template <int K, int N, int KSPLIT>
__global__ __launch_bounds__(256, 2)
void kan_gemm(const unsigned short* __restrict__ A,
              const unsigned short* __restrict__ B,
              float* __restrict__ P)
{
    __shared__ unsigned short As0[128 * 64], As1[128 * 64];   // 16 KB each
    __shared__ unsigned short Bs0[128 * 64], Bs1[128 * 64];   // total 64 KB

    const int tid  = threadIdx.x;
    const int lane = tid & 63;
    const int wave = tid >> 6;          // 0..3
    const int wm   = wave >> 1;         // wave row -> 64 batch rows
    const int wn   = wave & 1;          // wave col -> 64 out cols
    const int fr   = lane & 15;
    const int fq   = lane >> 4;

    // 2-D XCD chunk swizzle: each XCD (= wg&7 under round-robin dispatch, gridDim.x%8==0)
    // gets a compact CR x CC tile chunk -> A re-fetched 2x, B 4x per z (was 1-D: A up to 8x).
    constexpr int NBX = BATCH / 128;            // 32 row-tiles
    constexpr int NBY = N / 128;                // 16 or 4 col-tiles
    constexpr int NWG = NBX * NBY;
    constexpr int S   = NWG / 8;                // tiles per XCD chunk (64 or 16)
    constexpr int CC  = (NBY >= 8) ? 8 : NBY;   // chunk cols
    constexpr int CR  = S / CC;                 // chunk rows
    constexpr int GR  = NBX / CR;               // chunk-grid rows (GR * (NBY/CC) == 8)
    const int wg  = blockIdx.y * NBX + blockIdx.x;
    const int x   = wg & 7;
    const int idx = wg >> 3;                    // 0..S-1
    const int row0 = ((x % GR) * CR + idx % CR) * 128;
    const int col0 = ((x / GR) * CC + idx / CR) * 128;

    constexpr int KCH = K / KSPLIT;
    const int k0 = (int)blockIdx.z * KCH;

    const int srow = lane >> 3;           // 0..7: row within the wave's 8-row staging stripe
    const int scol = (lane & 7) * 16;     // byte col within the 128 B row

    auto STAGE = [&](unsigned short* Ad, unsigned short* Bd, int kt) {
        #pragma unroll
        for (int r = 0; r < 4; ++r) {
            const int rr = r * 32 + wave * 8;          // wave-uniform stripe base
            gload_lds16((const char*)A + ((size_t)(row0 + rr + srow) * K + (size_t)kt * 64) * 2 + scol,
                        (char*)&Ad[rr * 64]);
            gload_lds16((const char*)B + ((size_t)(col0 + rr + srow) * K + (size_t)kt * 64) * 2 + scol,
                        (char*)&Bd[rr * 64]);
        }
    };

    f32x4 acc[4][4] = {};

    const int kt0 = k0 >> 6, kt1 = (k0 + KCH) >> 6;
    unsigned short *Ac = As0, *An = As1, *Bc = Bs0, *Bn = Bs1;
    STAGE(Ac, Bc, kt0);                    // prologue: 8 loads in flight

    #pragma unroll 1
    for (int kt = kt0; kt < kt1; ++kt) {
        // Issue next tile's loads, then certify current tile's 8 landed (oldest-8 retired),
        // then publish via raw barrier. Next-tile loads stay in flight across the MFMA phase.
        if (kt + 1 < kt1) {
            STAGE(An, Bn, kt + 1);
            asm volatile("s_waitcnt vmcnt(8)" ::: "memory");
        } else {
            asm volatile("s_waitcnt vmcnt(0)" ::: "memory");
        }
        __builtin_amdgcn_s_barrier();
        __builtin_amdgcn_sched_barrier(0);   // keep ds_reads below the publish point

        #pragma unroll
        for (int ks = 0; ks < 2; ++ks) {
            bf16x8 af[4], bfm[4];
            #pragma unroll
            for (int m = 0; m < 4; ++m)
                af[m] = *(const bf16x8*)&Ac[(wm * 64 + m * 16 + fr) * 64 + ks * 32 + fq * 8];
            #pragma unroll
            for (int n = 0; n < 4; ++n)
                bfm[n] = *(const bf16x8*)&Bc[(wn * 64 + n * 16 + fr) * 64 + ks * 32 + fq * 8];
            #pragma unroll
            for (int m = 0; m < 4; ++m)
                #pragma unroll
                for (int n = 0; n < 4; ++n)
                    acc[m][n] = __builtin_amdgcn_mfma_f32_16x16x32_bf16(
                        af[m], bfm[n], acc[m][n], 0, 0, 0);
        }

        // All our ds_reads complete before any wave may overwrite this buffer next iter.
        asm volatile("s_waitcnt lgkmcnt(0)" ::: "memory");
        __builtin_amdgcn_s_barrier();

        unsigned short* t;
        t = Ac; Ac = An; An = t;
        t = Bc; Bc = Bn; Bn = t;
    }

    // Epilogue: write split-K partial plane. C/D layout: col = lane&15, row = (lane>>4)*4+reg.
    float* Pz = P + (size_t)blockIdx.z * BATCH * N;
    #pragma unroll
    for (int n = 0; n < 4; ++n) {
        const int gc = col0 + wn * 64 + n * 16 + fr;
        #pragma unroll
        for (int m = 0; m < 4; ++m) {
            const int gr0 = row0 + wm * 64 + m * 16 + fq * 4;
            #pragma unroll
            for (int q = 0; q < 4; ++q)
                Pz[(size_t)(gr0 + q) * N + gc] = acc[m][n][q];
        }
    }
}

extern "C" void kernel_launch(void* const* d_in, const int* in_sizes, int n_in,
                              void* d_out, int out_size, void* d_ws, size_t ws_size,
                              hipStream_t stream) {
    (void)in_sizes; (void)n_in; (void)ws_size; (void)out_size;
    const float* x  = (const float*)d_in[0];   // [4096][768]
    const float* C1 = (const float*)d_in[1];   // [2][2048][768][8]
    const float* b1 = (const float*)d_in[2];   // [2048]
    const float* C2 = (const float*)d_in[3];   // [2][2048][2048][8]
    const float* b2 = (const float*)d_in[4];   // [2048]
    const float* C3 = (const float*)d_in[5];   // [2][512][2048][8]
    const float* b3 = (const float*)d_in[6];   // [512]
    float* out = (float*)d_out;                // [4096][512]

    // Workspace layout, lifetime-aliased (proven layout from round 3). Peak 554 MB.
    char* ws = (char*)d_ws;
    const size_t SZ_A1  = (size_t)4096 * 12288 * 2;      // 100,663,296
    const size_t SZ_B1  = (size_t)2048 * 12288 * 2;      //  50,331,648
    const size_t SZ_P12 = (size_t)2 * 4096 * 2048 * 4;   //  67,108,864
    const size_t SZ_A2  = (size_t)4096 * 32768 * 2;      // 268,435,456
    unsigned short* A1 = (unsigned short*)(ws);
    unsigned short* B1 = (unsigned short*)(ws + SZ_A1);
    float*          P1 = (float*)(ws + SZ_A1 + SZ_B1);
    unsigned short* A2 = (unsigned short*)(ws + SZ_A1 + SZ_B1 + SZ_P12);
    unsigned short* B2 = (unsigned short*)(ws);                           // aliases dead A1+B1
    float*          P2 = (float*)(ws + SZ_A1 + SZ_B1 + SZ_P12 + SZ_A2);
    unsigned short* A3 = (unsigned short*)(ws);                           // aliases dead B2/P1
    unsigned short* B3 = (unsigned short*)(ws + SZ_A2);
    float*          P3 = (float*)(ws + SZ_A2 + (size_t)512 * 32768 * 2);

    // ---- layer 1: (4096 x 12288) x (2048 x 12288)^T, split-K x2 -> feats -> A2
    conv_C<768, 2048><<<dim3(768 / 256, 2048), 256, 0, stream>>>(C1, B1);
    feats_x_kernel<<<dim3((4096 * 768) / 256), 256, 0, stream>>>(x, A1);
    kan_gemm<12288, 2048, 2><<<dim3(32, 16, 2), 256, 0, stream>>>(A1, B1, P1);
    reduce_feats<2048, 2><<<dim3((BATCH * 2048) / 256), 256, 0, stream>>>(P1, b1, A2);

    // ---- layer 2: (4096 x 32768) x (2048 x 32768)^T, split-K x2 -> feats -> A3
    conv_C<2048, 2048><<<dim3(2048 / 256, 2048), 256, 0, stream>>>(C2, B2);
    kan_gemm<32768, 2048, 2><<<dim3(32, 16, 2), 256, 0, stream>>>(A2, B2, P2);
    reduce_feats<2048, 2><<<dim3((BATCH * 2048) / 256), 256, 0, stream>>>(P2, b2, A3);

    // ---- layer 3: (4096 x 32768) x (512 x 32768)^T, split-K x8, deterministic reduce
    conv_C<2048, 512><<<dim3(2048 / 256, 512), 256, 0, stream>>>(C3, B3);
    kan_gemm<32768, 512, 8><<<dim3(32, 4, 8), 256, 0, stream>>>(A3, B3, P3);
    reduce_out<512, 8><<<dim3((BATCH * 512 / 4) / 256), 256, 0, stream>>>(P3, b3, out);
}

// Round 5
// 1411.785 us; speedup vs baseline: 1.2288x; 1.2204x over previous
//
#include <hip/hip_runtime.h>

#define BATCH 4096

typedef __attribute__((ext_vector_type(8))) short bf16x8;
typedef __attribute__((ext_vector_type(4))) float f32x4;

// Manual RNE float->bf16 (round half to even), matches HW/NumPy for normal finite values.
__device__ __forceinline__ unsigned short f2bf(float f) {
    union { float f; unsigned u; } v; v.f = f;
    unsigned r = v.u + 0x7fffu + ((v.u >> 16) & 1u);
    return (unsigned short)(r >> 16);
}
__device__ __forceinline__ unsigned packbf(float a, float b) {
    return (unsigned)f2bf(a) | ((unsigned)f2bf(b) << 16);
}

// 16 features for one x: o[0..3] = cos(1x..8x) pairs, o[4..7] = sin(1x..8x) pairs (bf16x2).
__device__ __forceinline__ void feats16(float x, unsigned o[8]) {
    float c1 = __cosf(x), s1 = __sinf(x);
    float cs[8], sn[8];
    cs[0] = c1; sn[0] = s1;
    #pragma unroll
    for (int k = 1; k < 8; ++k) {
        cs[k] = c1 * cs[k-1] - s1 * sn[k-1];
        sn[k] = s1 * cs[k-1] + c1 * sn[k-1];
    }
    #pragma unroll
    for (int k = 0; k < 4; ++k) {
        o[k]     = packbf(cs[2*k], cs[2*k+1]);
        o[4 + k] = packbf(sn[2*k], sn[2*k+1]);
    }
}

// Async global->LDS, 16 B per lane. LDS dest is wave-uniform base; HW adds lane*16.
__device__ __forceinline__ void gload_lds16(const void* g, void* l) {
    __builtin_amdgcn_global_load_lds(
        (__attribute__((address_space(1))) void*)(g),
        (__attribute__((address_space(3))) void*)(l), 16, 0, 0);
}

// ---------------- one-shot precompute kernels ----------------

// C [2][OUT][IN][8] f32  ->  B [OUT][IN*16] bf16, k = i*16 + d*8 + g
template <int IN, int OUT>
__global__ void conv_C(const float* __restrict__ C, unsigned short* __restrict__ B) {
    const int i = blockIdx.x * 256 + threadIdx.x;
    const int j = blockIdx.y;
    const float* c0 = C + ((size_t)j * IN + i) * 8;            // d=0 (cos) plane
    const float* c1 = c0 + (size_t)OUT * IN * 8;               // d=1 (sin) plane
    const float4 a0 = *(const float4*)c0;
    const float4 a1 = *(const float4*)(c0 + 4);
    const float4 s0 = *(const float4*)c1;
    const float4 s1 = *(const float4*)(c1 + 4);
    unsigned short* dst = B + ((size_t)j * IN + i) * 16;
    *(uint4*)dst       = make_uint4(packbf(a0.x, a0.y), packbf(a0.z, a0.w),
                                    packbf(a1.x, a1.y), packbf(a1.z, a1.w));
    *(uint4*)(dst + 8) = make_uint4(packbf(s0.x, s0.y), packbf(s0.z, s0.w),
                                    packbf(s1.x, s1.y), packbf(s1.z, s1.w));
}

// x [4096][768] f32 -> A1 [4096][768*16] bf16 (features of the input layer)
__global__ void feats_x_kernel(const float* __restrict__ x, unsigned short* __restrict__ A) {
    const size_t idx = (size_t)blockIdx.x * 256 + threadIdx.x;   // (b,i) linear
    unsigned o[8];
    feats16(x[idx], o);
    unsigned short* dst = A + idx * 16;
    *(uint4*)dst       = make_uint4(o[0], o[1], o[2], o[3]);
    *(uint4*)(dst + 8) = make_uint4(o[4], o[5], o[6], o[7]);
}

// Deterministic split-K reduce + feature epilogue (fixed order -> bitwise-stable).
template <int N, int KSPLIT>
__global__ void reduce_feats(const float* __restrict__ P, const float* __restrict__ bias,
                             unsigned short* __restrict__ A) {
    const size_t idx = (size_t)blockIdx.x * 256 + threadIdx.x;   // (b,j) linear
    float s = P[idx];
    #pragma unroll
    for (int z = 1; z < KSPLIT; ++z) s += P[(size_t)z * BATCH * N + idx];
    s += bias[idx % N];
    unsigned o[8];
    feats16(s, o);
    unsigned short* dst = A + idx * 16;
    *(uint4*)dst       = make_uint4(o[0], o[1], o[2], o[3]);
    *(uint4*)(dst + 8) = make_uint4(o[4], o[5], o[6], o[7]);
}

// Deterministic split-K reduction: out[b][j] = sum_z P[z][b][j] + bias[j].
template <int N, int KSPLIT>
__global__ void reduce_out(const float* __restrict__ P, const float* __restrict__ bias,
                           float* __restrict__ out) {
    const size_t idx = ((size_t)blockIdx.x * 256 + threadIdx.x) * 4;   // float4 granule
    const int j = (int)(idx % N);                                       // N % 4 == 0
    float4 s = *(const float4*)(P + idx);
    #pragma unroll
    for (int z = 1; z < KSPLIT; ++z) {
        const float4 v = *(const float4*)(P + (size_t)z * BATCH * N + idx);
        s.x += v.x; s.y += v.y; s.z += v.z; s.w += v.w;
    }
    const float4 bv = *(const float4*)(bias + j);
    s.x += bv.x; s.y += bv.y; s.z += bv.z; s.w += bv.w;
    *(float4*)(out + idx) = s;
}

// ---------------- main bf16 GEMM: dbuf + counted vmcnt + T2 XOR swizzle ----------------
// A [4096][K] bf16 row-major, B [N][K] bf16 row-major (B^T GEMM).
// BK=64, 4 waves (2x2), 128x128 tile, double-buffered LDS, vmcnt(8) prefetch.
// T2 (rule #21, both-sides): LDS stays LINEAR (required by global_load_lds); the global
// SOURCE is pre-swizzled per-lane (chunk ^= row&7 within each 8-row stripe) and the
// ds_read applies the same XOR. Round-4 profile: 2.013e8 conflict-cycles/dispatch
// (16-way on the 128 B-stride fragment reads) was the critical path at MfmaUtil 24.5%.
template <int K, int N, int KSPLIT>
__global__ __launch_bounds__(256, 2)
void kan_gemm(const unsigned short* __restrict__ A,
              const unsigned short* __restrict__ B,
              float* __restrict__ P)
{
    __shared__ unsigned short As0[128 * 64], As1[128 * 64];   // 16 KB each
    __shared__ unsigned short Bs0[128 * 64], Bs1[128 * 64];   // total 64 KB

    const int tid  = threadIdx.x;
    const int lane = tid & 63;
    const int wave = tid >> 6;          // 0..3
    const int wm   = wave >> 1;         // wave row -> 64 batch rows
    const int wn   = wave & 1;          // wave col -> 64 out cols
    const int fr   = lane & 15;
    const int fq   = lane >> 4;

    // 2-D XCD chunk swizzle (kept from round 4: halved FETCH_SIZE).
    constexpr int NBX = BATCH / 128;            // 32 row-tiles
    constexpr int NBY = N / 128;                // 16 or 4 col-tiles
    constexpr int NWG = NBX * NBY;
    constexpr int S   = NWG / 8;                // tiles per XCD chunk
    constexpr int CC  = (NBY >= 8) ? 8 : NBY;   // chunk cols
    constexpr int CR  = S / CC;                 // chunk rows
    constexpr int GR  = NBX / CR;               // chunk-grid rows
    const int wg  = blockIdx.y * NBX + blockIdx.x;
    const int x   = wg & 7;
    const int idx = wg >> 3;
    const int row0 = ((x % GR) * CR + idx % CR) * 128;
    const int col0 = ((x / GR) * CC + idx / CR) * 128;

    constexpr int KCH = K / KSPLIT;
    const int k0 = (int)blockIdx.z * KCH;

    const int srow = lane >> 3;                        // 0..7: row within 8-row stripe
    const int scol = ((lane & 7) ^ srow) * 16;         // PRE-SWIZZLED global 16B-chunk

    auto STAGE = [&](unsigned short* Ad, unsigned short* Bd, int kt) {
        #pragma unroll
        for (int r = 0; r < 4; ++r) {
            const int rr = r * 32 + wave * 8;          // wave-uniform stripe base
            gload_lds16((const char*)A + ((size_t)(row0 + rr + srow) * K + (size_t)kt * 64) * 2 + scol,
                        (char*)&Ad[rr * 64]);
            gload_lds16((const char*)B + ((size_t)(col0 + rr + srow) * K + (size_t)kt * 64) * 2 + scol,
                        (char*)&Bd[rr * 64]);
        }
    };

    f32x4 acc[4][4] = {};

    const int kt0 = k0 >> 6, kt1 = (k0 + KCH) >> 6;
    unsigned short *Ac = As0, *An = As1, *Bc = Bs0, *Bn = Bs1;
    STAGE(Ac, Bc, kt0);                    // prologue: 8 loads in flight

    const int rx = fr & 7;                 // row&7 of every fragment row this lane reads

    #pragma unroll 1
    for (int kt = kt0; kt < kt1; ++kt) {
        // Issue next tile's loads, then certify current tile's 8 landed (oldest-8 retired),
        // then publish via raw barrier. Next-tile loads stay in flight across the MFMA phase.
        if (kt + 1 < kt1) {
            STAGE(An, Bn, kt + 1);
            asm volatile("s_waitcnt vmcnt(8)" ::: "memory");
        } else {
            asm volatile("s_waitcnt vmcnt(0)" ::: "memory");
        }
        __builtin_amdgcn_s_barrier();
        __builtin_amdgcn_sched_barrier(0);   // keep ds_reads below the publish point

        #pragma unroll
        for (int ks = 0; ks < 2; ++ks) {
            bf16x8 af[4], bfm[4];
            #pragma unroll
            for (int m = 0; m < 4; ++m)
                af[m] = *(const bf16x8*)&Ac[(wm * 64 + m * 16 + fr) * 64 +
                                            (((ks * 4 + fq) ^ rx) << 3)];
            #pragma unroll
            for (int n = 0; n < 4; ++n)
                bfm[n] = *(const bf16x8*)&Bc[(wn * 64 + n * 16 + fr) * 64 +
                                             (((ks * 4 + fq) ^ rx) << 3)];
            #pragma unroll
            for (int m = 0; m < 4; ++m)
                #pragma unroll
                for (int n = 0; n < 4; ++n)
                    acc[m][n] = __builtin_amdgcn_mfma_f32_16x16x32_bf16(
                        af[m], bfm[n], acc[m][n], 0, 0, 0);
        }

        // All our ds_reads complete before any wave may overwrite this buffer next iter.
        asm volatile("s_waitcnt lgkmcnt(0)" ::: "memory");
        __builtin_amdgcn_s_barrier();

        unsigned short* t;
        t = Ac; Ac = An; An = t;
        t = Bc; Bc = Bn; Bn = t;
    }

    // Epilogue: write split-K partial plane. C/D layout: col = lane&15, row = (lane>>4)*4+reg.
    float* Pz = P + (size_t)blockIdx.z * BATCH * N;
    #pragma unroll
    for (int n = 0; n < 4; ++n) {
        const int gc = col0 + wn * 64 + n * 16 + fr;
        #pragma unroll
        for (int m = 0; m < 4; ++m) {
            const int gr0 = row0 + wm * 64 + m * 16 + fq * 4;
            #pragma unroll
            for (int q = 0; q < 4; ++q)
                Pz[(size_t)(gr0 + q) * N + gc] = acc[m][n][q];
        }
    }
}

extern "C" void kernel_launch(void* const* d_in, const int* in_sizes, int n_in,
                              void* d_out, int out_size, void* d_ws, size_t ws_size,
                              hipStream_t stream) {
    (void)in_sizes; (void)n_in; (void)ws_size; (void)out_size;
    const float* x  = (const float*)d_in[0];   // [4096][768]
    const float* C1 = (const float*)d_in[1];   // [2][2048][768][8]
    const float* b1 = (const float*)d_in[2];   // [2048]
    const float* C2 = (const float*)d_in[3];   // [2][2048][2048][8]
    const float* b2 = (const float*)d_in[4];   // [2048]
    const float* C3 = (const float*)d_in[5];   // [2][512][2048][8]
    const float* b3 = (const float*)d_in[6];   // [512]
    float* out = (float*)d_out;                // [4096][512]

    // Workspace layout, lifetime-aliased (proven). Peak 554 MB.
    char* ws = (char*)d_ws;
    const size_t SZ_A1  = (size_t)4096 * 12288 * 2;      // 100,663,296
    const size_t SZ_B1  = (size_t)2048 * 12288 * 2;      //  50,331,648
    const size_t SZ_P12 = (size_t)2 * 4096 * 2048 * 4;   //  67,108,864
    const size_t SZ_A2  = (size_t)4096 * 32768 * 2;      // 268,435,456
    unsigned short* A1 = (unsigned short*)(ws);
    unsigned short* B1 = (unsigned short*)(ws + SZ_A1);
    float*          P1 = (float*)(ws + SZ_A1 + SZ_B1);
    unsigned short* A2 = (unsigned short*)(ws + SZ_A1 + SZ_B1 + SZ_P12);
    unsigned short* B2 = (unsigned short*)(ws);                           // aliases dead A1+B1
    float*          P2 = (float*)(ws + SZ_A1 + SZ_B1 + SZ_P12 + SZ_A2);
    unsigned short* A3 = (unsigned short*)(ws);                           // aliases dead B2/P1
    unsigned short* B3 = (unsigned short*)(ws + SZ_A2);
    float*          P3 = (float*)(ws + SZ_A2 + (size_t)512 * 32768 * 2);

    // ---- layer 1: (4096 x 12288) x (2048 x 12288)^T, split-K x2 -> feats -> A2
    conv_C<768, 2048><<<dim3(768 / 256, 2048), 256, 0, stream>>>(C1, B1);
    feats_x_kernel<<<dim3((4096 * 768) / 256), 256, 0, stream>>>(x, A1);
    kan_gemm<12288, 2048, 2><<<dim3(32, 16, 2), 256, 0, stream>>>(A1, B1, P1);
    reduce_feats<2048, 2><<<dim3((BATCH * 2048) / 256), 256, 0, stream>>>(P1, b1, A2);

    // ---- layer 2: (4096 x 32768) x (2048 x 32768)^T, split-K x2 -> feats -> A3
    conv_C<2048, 2048><<<dim3(2048 / 256, 2048), 256, 0, stream>>>(C2, B2);
    kan_gemm<32768, 2048, 2><<<dim3(32, 16, 2), 256, 0, stream>>>(A2, B2, P2);
    reduce_feats<2048, 2><<<dim3((BATCH * 2048) / 256), 256, 0, stream>>>(P2, b2, A3);

    // ---- layer 3: (4096 x 32768) x (512 x 32768)^T, split-K x8, deterministic reduce
    conv_C<2048, 512><<<dim3(2048 / 256, 512), 256, 0, stream>>>(C3, B3);
    kan_gemm<32768, 512, 8><<<dim3(32, 4, 8), 256, 0, stream>>>(A3, B3, P3);
    reduce_out<512, 8><<<dim3((BATCH * 512 / 4) / 256), 256, 0, stream>>>(P3, b3, out);
}

// Round 6
// 1146.701 us; speedup vs baseline: 1.5129x; 1.2312x over previous
//
#include <hip/hip_runtime.h>

#define BATCH 4096

typedef __attribute__((ext_vector_type(8))) short bf16x8;
typedef __attribute__((ext_vector_type(4))) float f32x4;

// Manual RNE float->bf16 (round half to even), matches HW/NumPy for normal finite values.
__device__ __forceinline__ unsigned short f2bf(float f) {
    union { float f; unsigned u; } v; v.f = f;
    unsigned r = v.u + 0x7fffu + ((v.u >> 16) & 1u);
    return (unsigned short)(r >> 16);
}
__device__ __forceinline__ unsigned packbf(float a, float b) {
    return (unsigned)f2bf(a) | ((unsigned)f2bf(b) << 16);
}

// 16 features for one x: o[0..3] = cos(1x..8x) pairs, o[4..7] = sin(1x..8x) pairs (bf16x2).
__device__ __forceinline__ void feats16(float x, unsigned o[8]) {
    float c1 = __cosf(x), s1 = __sinf(x);
    float cs[8], sn[8];
    cs[0] = c1; sn[0] = s1;
    #pragma unroll
    for (int k = 1; k < 8; ++k) {
        cs[k] = c1 * cs[k-1] - s1 * sn[k-1];
        sn[k] = s1 * cs[k-1] + c1 * sn[k-1];
    }
    #pragma unroll
    for (int k = 0; k < 4; ++k) {
        o[k]     = packbf(cs[2*k], cs[2*k+1]);
        o[4 + k] = packbf(sn[2*k], sn[2*k+1]);
    }
}

// Async global->LDS, 16 B per lane. LDS dest is wave-uniform base; HW adds lane*16.
__device__ __forceinline__ void gload_lds16(const void* g, void* l) {
    __builtin_amdgcn_global_load_lds(
        (__attribute__((address_space(1))) void*)(g),
        (__attribute__((address_space(3))) void*)(l), 16, 0, 0);
}

// ---------------- one-shot precompute kernels ----------------

// C [2][OUT][IN][8] f32  ->  B [OUT][IN*16] bf16, k = i*16 + d*8 + g
template <int IN, int OUT>
__global__ void conv_C(const float* __restrict__ C, unsigned short* __restrict__ B) {
    const int i = blockIdx.x * 256 + threadIdx.x;
    const int j = blockIdx.y;
    const float* c0 = C + ((size_t)j * IN + i) * 8;            // d=0 (cos) plane
    const float* c1 = c0 + (size_t)OUT * IN * 8;               // d=1 (sin) plane
    const float4 a0 = *(const float4*)c0;
    const float4 a1 = *(const float4*)(c0 + 4);
    const float4 s0 = *(const float4*)c1;
    const float4 s1 = *(const float4*)(c1 + 4);
    unsigned short* dst = B + ((size_t)j * IN + i) * 16;
    *(uint4*)dst       = make_uint4(packbf(a0.x, a0.y), packbf(a0.z, a0.w),
                                    packbf(a1.x, a1.y), packbf(a1.z, a1.w));
    *(uint4*)(dst + 8) = make_uint4(packbf(s0.x, s0.y), packbf(s0.z, s0.w),
                                    packbf(s1.x, s1.y), packbf(s1.z, s1.w));
}

// x [4096][768] f32 -> A1 [4096][768*16] bf16 (features of the input layer)
__global__ void feats_x_kernel(const float* __restrict__ x, unsigned short* __restrict__ A) {
    const size_t idx = (size_t)blockIdx.x * 256 + threadIdx.x;   // (b,i) linear
    unsigned o[8];
    feats16(x[idx], o);
    unsigned short* dst = A + idx * 16;
    *(uint4*)dst       = make_uint4(o[0], o[1], o[2], o[3]);
    *(uint4*)(dst + 8) = make_uint4(o[4], o[5], o[6], o[7]);
}

// Deterministic split-K reduce + feature epilogue (fixed order -> bitwise-stable).
template <int N, int KSPLIT>
__global__ void reduce_feats(const float* __restrict__ P, const float* __restrict__ bias,
                             unsigned short* __restrict__ A) {
    const size_t idx = (size_t)blockIdx.x * 256 + threadIdx.x;   // (b,j) linear
    float s = P[idx];
    #pragma unroll
    for (int z = 1; z < KSPLIT; ++z) s += P[(size_t)z * BATCH * N + idx];
    s += bias[idx % N];
    unsigned o[8];
    feats16(s, o);
    unsigned short* dst = A + idx * 16;
    *(uint4*)dst       = make_uint4(o[0], o[1], o[2], o[3]);
    *(uint4*)(dst + 8) = make_uint4(o[4], o[5], o[6], o[7]);
}

// Deterministic split-K reduction: out[b][j] = sum_z P[z][b][j] + bias[j].
template <int N, int KSPLIT>
__global__ void reduce_out(const float* __restrict__ P, const float* __restrict__ bias,
                           float* __restrict__ out) {
    const size_t idx = ((size_t)blockIdx.x * 256 + threadIdx.x) * 4;   // float4 granule
    const int j = (int)(idx % N);                                       // N % 4 == 0
    float4 s = *(const float4*)(P + idx);
    #pragma unroll
    for (int z = 1; z < KSPLIT; ++z) {
        const float4 v = *(const float4*)(P + (size_t)z * BATCH * N + idx);
        s.x += v.x; s.y += v.y; s.z += v.z; s.w += v.w;
    }
    const float4 bv = *(const float4*)(bias + j);
    s.x += bv.x; s.y += bv.y; s.z += bv.z; s.w += bv.w;
    *(float4*)(out + idx) = s;
}

// ------------- main bf16 GEMM: 256x256 tile, 8 waves, 4-phase/K-tile schedule -------------
// A [4096][K] bf16 row-major, B [N][K] bf16 row-major (B^T GEMM).
// 8 waves (2 wm x 4 wn), wave tile 128x64, BK=64. LDS 128 KB:
//   As/Bs[2 buf][2 half(128 rows)][128][64], double-buffered, XOR-swizzled chunks
//   (linear gload_lds dest + pre-swizzled global source + swizzled ds_read; round-5 verified).
// Per K-tile t (buf b=t&1), 4 phases, each: {ds_read regs | stage 1 half-tile} ->
//   barrier -> lgkmcnt(0) -> sched_barrier(0) -> setprio(1) -> 16 MFMA -> setprio(0) -> barrier.
//   P1: read all B-frags + A(m0..3); stage B1(t+1)->buf[b^1]     (region dead since t-1 P1)
//   P2: read A(m4..7);               stage B0(t+2)->buf[b]       (B(t) reads done end-P1)
//   P3:                              stage A0(t+2)->buf[b]       (A(t) reads done end-P2)
//   P4:                              stage A1(t+2)->buf[b]; vmcnt(6)  (certifies t+1 landed)
// vmcnt(6) = 3 half-tiles in flight (T4, never 0 mid-loop). Tail tiles drain with vmcnt(0).
template <int K, int N, int KSPLIT>
__global__ __launch_bounds__(512, 2)
void kan_gemm(const unsigned short* __restrict__ A,
              const unsigned short* __restrict__ B,
              float* __restrict__ P)
{
    __shared__ unsigned short As[2 * 2 * 128 * 64];   // 64 KB
    __shared__ unsigned short Bs[2 * 2 * 128 * 64];   // 64 KB

    const int tid  = threadIdx.x;
    const int lane = tid & 63;
    const int wave = tid >> 6;          // 0..7
    const int wm   = wave >> 2;         // 0..1: wave row -> 128 batch rows
    const int wn   = wave & 3;          // 0..3: wave col -> 64 out cols
    const int fr   = lane & 15;
    const int fq   = lane >> 4;

    // 2-D XCD chunk swizzle over 256-tiles (ported from round 4).
    constexpr int NBX = BATCH / 256;            // 16 row-tiles
    constexpr int NBY = N / 256;                // 8 or 2 col-tiles
    constexpr int NWG = NBX * NBY;
    constexpr int S   = NWG / 8;
    constexpr int CC  = (NBY >= 8) ? 8 : NBY;
    constexpr int CR  = S / CC;
    constexpr int GR  = NBX / CR;
    const int wg  = blockIdx.y * NBX + blockIdx.x;
    const int xc  = wg & 7;
    const int ci  = wg >> 3;
    const int row0 = ((xc % GR) * CR + ci % CR) * 256;
    const int col0 = ((xc / GR) * CC + ci / CR) * 256;

    constexpr int KCH = K / KSPLIT;
    const int kt0 = ((int)blockIdx.z * KCH) >> 6;
    const int nt  = KCH >> 6;

    const int srow = lane >> 3;                   // 0..7 within the wave's 8-row stripe
    const int scol = ((lane & 7) ^ srow) * 16;    // pre-swizzled global 16B chunk (bytes)

    // Stage one half-tile (128 rows x 64 k) = 2 gload rounds (64 rows each).
    auto STA = [&](int b, int h, int kt) {
        #pragma unroll
        for (int r2 = 0; r2 < 2; ++r2)
            gload_lds16((const char*)A +
                        ((size_t)(row0 + h * 128 + r2 * 64 + wave * 8 + srow) * K + (size_t)kt * 64) * 2 + scol,
                        (char*)&As[((b * 2 + h) * 128 + r2 * 64 + wave * 8) * 64]);
    };
    auto STB = [&](int b, int h, int kt) {
        #pragma unroll
        for (int r2 = 0; r2 < 2; ++r2)
            gload_lds16((const char*)B +
                        ((size_t)(col0 + h * 128 + r2 * 64 + wave * 8 + srow) * K + (size_t)kt * 64) * 2 + scol,
                        (char*)&Bs[((b * 2 + h) * 128 + r2 * 64 + wave * 8) * 64]);
    };
    // Swizzled fragment reads (chunk ^= row&7, row&7 == fr&7 for all frag rows).
    auto LDA = [&](int b, int m, int ks) -> bf16x8 {
        return *(const bf16x8*)&As[((b * 2 + wm) * 128 + m * 16 + fr) * 64 +
                                   (((ks * 4 + fq) ^ (fr & 7)) << 3)];
    };
    auto LDB = [&](int b, int n, int ks) -> bf16x8 {
        return *(const bf16x8*)&Bs[((b * 2 + (wn >> 1)) * 128 + (wn & 1) * 64 + n * 16 + fr) * 64 +
                                   (((ks * 4 + fq) ^ (fr & 7)) << 3)];
    };

    f32x4 acc[8][4] = {};

    // Prologue: tile kt0 complete (4 halves) + tile kt0+1 {A0,A1,B0} = 14 loads; keep 6 in flight.
    STA(0, 0, kt0); STA(0, 1, kt0); STB(0, 0, kt0); STB(0, 1, kt0);
    STA(1, 0, kt0 + 1); STA(1, 1, kt0 + 1); STB(1, 0, kt0 + 1);
    asm volatile("s_waitcnt vmcnt(6)" ::: "memory");
    __builtin_amdgcn_s_barrier();

    #pragma unroll 1
    for (int t = 0; t < nt; ++t) {
        const int b  = t & 1;
        const int kt = kt0 + t;
        bf16x8 bF[8], aFa[8], aFb[8];

        // ---- P1: all B-frags (8) + A m0..3 (8); stage B1(t+1) -> other buffer
        #pragma unroll
        for (int n = 0; n < 4; ++n) { bF[n * 2] = LDB(b, n, 0); bF[n * 2 + 1] = LDB(b, n, 1); }
        #pragma unroll
        for (int mm = 0; mm < 4; ++mm) { aFa[mm * 2] = LDA(b, mm, 0); aFa[mm * 2 + 1] = LDA(b, mm, 1); }
        if (t + 1 < nt) STB(b ^ 1, 1, kt + 1);
        __builtin_amdgcn_s_barrier();
        asm volatile("s_waitcnt lgkmcnt(0)" ::: "memory");
        __builtin_amdgcn_sched_barrier(0);
        __builtin_amdgcn_s_setprio(1);
        #pragma unroll
        for (int ks = 0; ks < 2; ++ks)
            #pragma unroll
            for (int mm = 0; mm < 2; ++mm)
                #pragma unroll
                for (int n = 0; n < 4; ++n)
                    acc[mm][n] = __builtin_amdgcn_mfma_f32_16x16x32_bf16(
                        aFa[mm * 2 + ks], bF[n * 2 + ks], acc[mm][n], 0, 0, 0);
        __builtin_amdgcn_s_setprio(0);
        __builtin_amdgcn_s_barrier();

        // ---- P2: A m4..7 (8); stage B0(t+2) -> this buffer (B(t) reads finished at end-P1)
        #pragma unroll
        for (int mm = 0; mm < 4; ++mm) { aFb[mm * 2] = LDA(b, 4 + mm, 0); aFb[mm * 2 + 1] = LDA(b, 4 + mm, 1); }
        if (t + 2 < nt) STB(b, 0, kt + 2);
        __builtin_amdgcn_s_barrier();
        asm volatile("s_waitcnt lgkmcnt(0)" ::: "memory");
        __builtin_amdgcn_sched_barrier(0);
        __builtin_amdgcn_s_setprio(1);
        #pragma unroll
        for (int ks = 0; ks < 2; ++ks)
            #pragma unroll
            for (int mm = 0; mm < 2; ++mm)
                #pragma unroll
                for (int n = 0; n < 4; ++n)
                    acc[2 + mm][n] = __builtin_amdgcn_mfma_f32_16x16x32_bf16(
                        aFa[(2 + mm) * 2 + ks], bF[n * 2 + ks], acc[2 + mm][n], 0, 0, 0);
        __builtin_amdgcn_s_setprio(0);
        __builtin_amdgcn_s_barrier();

        // ---- P3: stage A0(t+2) (A(t) reads finished at end-P2)
        if (t + 2 < nt) STA(b, 0, kt + 2);
        __builtin_amdgcn_s_barrier();
        __builtin_amdgcn_sched_barrier(0);
        __builtin_amdgcn_s_setprio(1);
        #pragma unroll
        for (int ks = 0; ks < 2; ++ks)
            #pragma unroll
            for (int mm = 0; mm < 2; ++mm)
                #pragma unroll
                for (int n = 0; n < 4; ++n)
                    acc[4 + mm][n] = __builtin_amdgcn_mfma_f32_16x16x32_bf16(
                        aFb[mm * 2 + ks], bF[n * 2 + ks], acc[4 + mm][n], 0, 0, 0);
        __builtin_amdgcn_s_setprio(0);
        __builtin_amdgcn_s_barrier();

        // ---- P4: stage A1(t+2); counted vmcnt certifies tile t+1 fully landed
        if (t + 2 < nt) {
            STA(b, 1, kt + 2);
            asm volatile("s_waitcnt vmcnt(6)" ::: "memory");
        } else {
            asm volatile("s_waitcnt vmcnt(0)" ::: "memory");
        }
        __builtin_amdgcn_s_barrier();
        __builtin_amdgcn_sched_barrier(0);
        __builtin_amdgcn_s_setprio(1);
        #pragma unroll
        for (int ks = 0; ks < 2; ++ks)
            #pragma unroll
            for (int mm = 0; mm < 2; ++mm)
                #pragma unroll
                for (int n = 0; n < 4; ++n)
                    acc[6 + mm][n] = __builtin_amdgcn_mfma_f32_16x16x32_bf16(
                        aFb[(2 + mm) * 2 + ks], bF[n * 2 + ks], acc[6 + mm][n], 0, 0, 0);
        __builtin_amdgcn_s_setprio(0);
        __builtin_amdgcn_s_barrier();
    }

    // Epilogue: split-K partial plane. C/D layout: col = lane&15, row = (lane>>4)*4+reg.
    float* Pz = P + (size_t)blockIdx.z * BATCH * N;
    #pragma unroll
    for (int m = 0; m < 8; ++m) {
        const int gr0 = row0 + wm * 128 + m * 16 + fq * 4;
        #pragma unroll
        for (int n = 0; n < 4; ++n) {
            const int gc = col0 + wn * 64 + n * 16 + fr;
            #pragma unroll
            for (int q = 0; q < 4; ++q)
                Pz[(size_t)(gr0 + q) * N + gc] = acc[m][n][q];
        }
    }
}

extern "C" void kernel_launch(void* const* d_in, const int* in_sizes, int n_in,
                              void* d_out, int out_size, void* d_ws, size_t ws_size,
                              hipStream_t stream) {
    (void)in_sizes; (void)n_in; (void)ws_size; (void)out_size;
    const float* x  = (const float*)d_in[0];   // [4096][768]
    const float* C1 = (const float*)d_in[1];   // [2][2048][768][8]
    const float* b1 = (const float*)d_in[2];   // [2048]
    const float* C2 = (const float*)d_in[3];   // [2][2048][2048][8]
    const float* b2 = (const float*)d_in[4];   // [2048]
    const float* C3 = (const float*)d_in[5];   // [2][512][2048][8]
    const float* b3 = (const float*)d_in[6];   // [512]
    float* out = (float*)d_out;                // [4096][512]

    // Workspace layout, lifetime-aliased (proven). Peak 554 MB.
    char* ws = (char*)d_ws;
    const size_t SZ_A1  = (size_t)4096 * 12288 * 2;      // 100,663,296
    const size_t SZ_B1  = (size_t)2048 * 12288 * 2;      //  50,331,648
    const size_t SZ_P12 = (size_t)2 * 4096 * 2048 * 4;   //  67,108,864
    const size_t SZ_A2  = (size_t)4096 * 32768 * 2;      // 268,435,456
    unsigned short* A1 = (unsigned short*)(ws);
    unsigned short* B1 = (unsigned short*)(ws + SZ_A1);
    float*          P1 = (float*)(ws + SZ_A1 + SZ_B1);
    unsigned short* A2 = (unsigned short*)(ws + SZ_A1 + SZ_B1 + SZ_P12);
    unsigned short* B2 = (unsigned short*)(ws);                           // aliases dead A1+B1
    float*          P2 = (float*)(ws + SZ_A1 + SZ_B1 + SZ_P12 + SZ_A2);
    unsigned short* A3 = (unsigned short*)(ws);                           // aliases dead B2/P1
    unsigned short* B3 = (unsigned short*)(ws + SZ_A2);
    float*          P3 = (float*)(ws + SZ_A2 + (size_t)512 * 32768 * 2);

    // ---- layer 1: (4096 x 12288) x (2048 x 12288)^T, split-K x2 -> feats -> A2
    conv_C<768, 2048><<<dim3(768 / 256, 2048), 256, 0, stream>>>(C1, B1);
    feats_x_kernel<<<dim3((4096 * 768) / 256), 256, 0, stream>>>(x, A1);
    kan_gemm<12288, 2048, 2><<<dim3(16, 8, 2), 512, 0, stream>>>(A1, B1, P1);
    reduce_feats<2048, 2><<<dim3((BATCH * 2048) / 256), 256, 0, stream>>>(P1, b1, A2);

    // ---- layer 2: (4096 x 32768) x (2048 x 32768)^T, split-K x2 -> feats -> A3
    conv_C<2048, 2048><<<dim3(2048 / 256, 2048), 256, 0, stream>>>(C2, B2);
    kan_gemm<32768, 2048, 2><<<dim3(16, 8, 2), 512, 0, stream>>>(A2, B2, P2);
    reduce_feats<2048, 2><<<dim3((BATCH * 2048) / 256), 256, 0, stream>>>(P2, b2, A3);

    // ---- layer 3: (4096 x 32768) x (512 x 32768)^T, split-K x8, deterministic reduce
    conv_C<2048, 512><<<dim3(2048 / 256, 512), 256, 0, stream>>>(C3, B3);
    kan_gemm<32768, 512, 8><<<dim3(16, 2, 8), 512, 0, stream>>>(A3, B3, P3);
    reduce_out<512, 8><<<dim3((BATCH * 512 / 4) / 256), 256, 0, stream>>>(P3, b3, out);
}